// Round 9
// baseline (319.634 us; speedup 1.0000x reference)
//
#include <hip/hip_runtime.h>

typedef _Float16 half8 __attribute__((ext_vector_type(8)));
typedef float f32x4 __attribute__((ext_vector_type(4)));
typedef float f32x2 __attribute__((ext_vector_type(2)));

#define TT   512
#define BB   16      // batch cols per block
#define HH   50
#define NW   13      // 13 waves, 1 M-tile each (208 padded gate rows)
#define NTHR (NW * 64)
#define L2E  1.44269504088896340736f

__device__ __forceinline__ float rcp_f(float x) { return __builtin_amdgcn_rcpf(x); }
__device__ __forceinline__ float exp2_f(float x) { return __builtin_amdgcn_exp2f(x); }

// Scalar fused LSTM cell update (5 exp2 + 2 rcp).
// Preacts prescaled: i,f,o rows by -log2e, g rows by +2log2e.
__device__ __forceinline__ float cell_update(f32x4 a, float& c) {
    float ei = exp2_f(a[0]);
    float ef = exp2_f(a[1]);
    float eg = exp2_f(a[2]);
    float eo = exp2_f(a[3]);
    float A  = 1.0f + ei;
    float Bv = 1.0f + ef;
    float G1 = eg + 1.0f;
    float G2 = eg - 1.0f;
    float AG = A * G1;
    float num = fmaf(c, AG, Bv * G2);
    float cn = num * rcp_f(Bv * AG);
    c = cn;
    float ec = exp2_f(cn * (2.0f * L2E));
    return (ec - 1.0f) * rcp_f((1.0f + eo) * (ec + 1.0f));
}

// Packed dual-layer update: both layers' cell updates as f32x2 (v_pk_* VALU).
__device__ __forceinline__ void cell_update2(const f32x4& a0, const f32x4& a1,
                                             float& c0, float& c1,
                                             float& hv0, float& hv1) {
    f32x2 ei = {exp2_f(a0[0]), exp2_f(a1[0])};
    f32x2 ef = {exp2_f(a0[1]), exp2_f(a1[1])};
    f32x2 eg = {exp2_f(a0[2]), exp2_f(a1[2])};
    f32x2 eo = {exp2_f(a0[3]), exp2_f(a1[3])};
    const f32x2 one = {1.0f, 1.0f};
    f32x2 A  = one + ei;
    f32x2 Bv = one + ef;
    f32x2 G1 = one + eg;
    f32x2 G2 = eg - one;
    f32x2 AG = A * G1;
    f32x2 cc = {c0, c1};
    f32x2 num = cc * AG + Bv * G2;
    f32x2 den = Bv * AG;
    f32x2 r   = {rcp_f(den[0]), rcp_f(den[1])};
    f32x2 cn  = num * r;
    c0 = cn[0]; c1 = cn[1];
    f32x2 ec = {exp2_f(cn[0] * (2.0f * L2E)), exp2_f(cn[1] * (2.0f * L2E))};
    f32x2 hn = ec - one;
    f32x2 hd = (one + eo) * (ec + one);
    f32x2 rh = {rcp_f(hd[0]), rcp_f(hd[1])};
    f32x2 hh = hn * rh;
    hv0 = hh[0]; hv1 = hh[1];
}

__global__ __launch_bounds__(NTHR, 1) void lstm2_pk2(
    const float* __restrict__ x,      // [B, T]
    const float* __restrict__ W_ih0,  // [200, 1]
    const float* __restrict__ W_hh0,  // [200, 50]
    const float* __restrict__ b_ih0,  // [200]
    const float* __restrict__ b_hh0,  // [200]
    const float* __restrict__ W_ih1,  // [200, 50]
    const float* __restrict__ W_hh1,  // [200, 50]
    const float* __restrict__ b_ih1,  // [200]
    const float* __restrict__ b_hh1,  // [200]
    const float* __restrict__ W_fc,   // [4, 50]
    const float* __restrict__ b_fc,   // [4]
    float* __restrict__ out)          // [B, 4]
{
    // h exchange: [parity][kt][hi][col][8 f16] -> one lane-linear b128 per frag
    __shared__ __align__(16) _Float16 hb0[2][2][4][16][8];   // 4 KB
    __shared__ __align__(16) _Float16 hb1[2][2][4][16][8];   // 4 KB
    __shared__ float x_lds[BB][TT + 10];                     // ~33 KB
    __shared__ float h1f[64][BB + 1];                        // final h1 (fp32)

    const int tid  = threadIdx.x;
    const int lane = tid & 63;
    const int wid  = tid >> 6;        // 13 waves; tile = wid
    const int col  = lane & 15;       // batch col
    const int hi   = lane >> 4;
    const int am   = lane & 15;       // A row within tile
    const int ak   = lane >> 4;       // A k-group
    const int b0g  = blockIdx.x * BB;
    // x-slot duty: wave 9 (on a 3-wave SIMD) writes h0 slot 50 <- x_{s+1};
    // wave 12 (straggler SIMD) skips its colliding unit-50 write.
    const bool xduty = (wid == 9);

    // ---- stage x; zero t=TT pad column ----
    for (int i = tid; i < BB * TT; i += NTHR) {
        int bi = i >> 9, ti = i & (TT - 1);
        x_lds[bi][ti] = x[(size_t)(b0g + bi) * TT + ti];
    }
    if (tid < BB) x_lds[tid][TT] = 0.0f;
    // ---- zero both parities of both h buffers ----
    for (int i = tid; i < 1024; i += NTHR) {
        ((unsigned*)hb0)[i] = 0u;
        ((unsigned*)hb1)[i] = 0u;
    }

    // ---- stationary A-frags (f16), gate rows reordered to 4u+type.
    //      Row scales: i,f,o -> -log2e ; g -> +2log2e. k=50 of W_hh0 carries W_ih0.
    half8 wA[2], wI[2], wH[2];
    f32x4 b0v = {}, b1v = {};
    {
        const int tile = wid;
        const int grow = tile * 16 + am;
        const int uu = grow >> 2, ty = grow & 3;
        const float rs = (ty == 2) ? 2.0f * L2E : -L2E;
        const bool ok = (uu < HH);
        const int gsrc = ty * HH + uu;
        for (int kt = 0; kt < 2; ++kt) {
            half8 a0 = {}, a1 = {}, a2 = {};
            for (int j = 0; j < 8; ++j) {
                int k = kt * 32 + ((j >> 2) << 4) + ak * 4 + (j & 3);
                if (ok) {
                    if (k < HH) {
                        a0[j] = (_Float16)(rs * W_hh0[gsrc * HH + k]);
                        a1[j] = (_Float16)(rs * W_ih1[gsrc * HH + k]);
                        a2[j] = (_Float16)(rs * W_hh1[gsrc * HH + k]);
                    } else if (k == 50) {
                        a0[j] = (_Float16)(rs * W_ih0[gsrc]);   // x rides h0 slot 50
                    }
                }
            }
            wA[kt] = a0; wI[kt] = a1; wH[kt] = a2;
        }
        const int u = tile * 4 + hi;
        if (u < HH)
            for (int r = 0; r < 4; ++r) {
                float s = (r == 2) ? 2.0f * L2E : -L2E;
                int g = r * HH + u;
                b0v[r] = s * (b_ih0[g] + b_hh0[g]);
                b1v[r] = s * (b_ih1[g] + b_hh1[g]);
            }
    }
    const int uown = wid * 4 + hi;
    const bool skip0 = (wid == 12 && hi == 2);   // unit 50: written by wave 9 (x) instead
    const int wkt = uown >> 5, whi = (uown & 15) >> 2;
    const int wsl = (uown & 3) | (((uown >> 4) & 1) << 2);
    float c0 = 0.0f, c1 = 0.0f;

    __syncthreads();
    if (tid < 16) hb0[0][1][0][tid][6] = (_Float16)x[(size_t)(b0g + tid) * TT];  // x_0 seed
    __syncthreads();

    // ---- full interior step: L0(s) || L1(s-1), reads parity p, writes p^1 ----
    auto full_step = [&](int s, int p) {
        const int q = p ^ 1;
        half8 h0k0 = *(const half8*)&hb0[p][0][hi][col][0];
        half8 h0k1 = *(const half8*)&hb0[p][1][hi][col][0];
        half8 h1k0 = *(const half8*)&hb1[p][0][hi][col][0];
        half8 h1k1 = *(const half8*)&hb1[p][1][hi][col][0];

        f32x4 a0 = __builtin_amdgcn_mfma_f32_16x16x32_f16(wA[0], h0k0, b0v, 0, 0, 0);
        a0       = __builtin_amdgcn_mfma_f32_16x16x32_f16(wA[1], h0k1, a0, 0, 0, 0);
        f32x4 aA = __builtin_amdgcn_mfma_f32_16x16x32_f16(wI[0], h0k0, b1v, 0, 0, 0);
        aA       = __builtin_amdgcn_mfma_f32_16x16x32_f16(wI[1], h0k1, aA, 0, 0, 0);
        f32x4 aB = {};
        aB       = __builtin_amdgcn_mfma_f32_16x16x32_f16(wH[0], h1k0, aB, 0, 0, 0);
        aB       = __builtin_amdgcn_mfma_f32_16x16x32_f16(wH[1], h1k1, aB, 0, 0, 0);
        f32x4 a1 = aA + aB;

        __builtin_amdgcn_s_setprio(1);            // tail: push stragglers to the barrier
        if (xduty) {
            if (lane < 16)                        // one writer per col: slot 50 <- x_{s+1}
                hb0[q][1][0][col][6] = (_Float16)x_lds[col][s + 1];
        }
        float hv0, hv1;
        cell_update2(a0, a1, c0, c1, hv0, hv1);
        if (!skip0) hb0[q][wkt][whi][col][wsl] = (_Float16)hv0;
        hb1[q][wkt][whi][col][wsl] = (_Float16)hv1;
        __builtin_amdgcn_s_setprio(0);
        __syncthreads();
    };

    // ---- s = 0 (p=0): L0 only ----
    {
        half8 h0k0 = *(const half8*)&hb0[0][0][hi][col][0];
        half8 h0k1 = *(const half8*)&hb0[0][1][hi][col][0];
        f32x4 a = __builtin_amdgcn_mfma_f32_16x16x32_f16(wA[0], h0k0, b0v, 0, 0, 0);
        a       = __builtin_amdgcn_mfma_f32_16x16x32_f16(wA[1], h0k1, a, 0, 0, 0);
        float h = cell_update(a, c0);
        if (xduty && lane < 16) hb0[1][1][0][col][6] = (_Float16)x_lds[col][1];
        if (!skip0) hb0[1][wkt][whi][col][wsl] = (_Float16)h;
        __syncthreads();
    }
    // ---- interior s = 1..510, unrolled by 2 with literal parity ----
    for (int s = 1; s <= TT - 3; s += 2) {
        full_step(s, 1);
        full_step(s + 1, 0);
    }
    full_step(TT - 1, 1);   // s = 511
    // ---- s = 512 (p=0): L1 only, stash final h1 ----
    {
        half8 h0k0 = *(const half8*)&hb0[0][0][hi][col][0];
        half8 h0k1 = *(const half8*)&hb0[0][1][hi][col][0];
        half8 h1k0 = *(const half8*)&hb1[0][0][hi][col][0];
        half8 h1k1 = *(const half8*)&hb1[0][1][hi][col][0];
        f32x4 aA = __builtin_amdgcn_mfma_f32_16x16x32_f16(wI[0], h0k0, b1v, 0, 0, 0);
        aA       = __builtin_amdgcn_mfma_f32_16x16x32_f16(wI[1], h0k1, aA, 0, 0, 0);
        f32x4 aB = {};
        aB       = __builtin_amdgcn_mfma_f32_16x16x32_f16(wH[0], h1k0, aB, 0, 0, 0);
        aB       = __builtin_amdgcn_mfma_f32_16x16x32_f16(wH[1], h1k1, aB, 0, 0, 0);
        f32x4 a  = aA + aB;
        float h = cell_update(a, c1);
        h1f[uown][col] = h;
        __syncthreads();
    }

    // ---- linear head: out[b][o] = h1[b][:50] . W_fc[o][:] + b_fc[o] ----
    if (tid < BB * 4) {
        int b = tid >> 2, o = tid & 3;
        float acc = b_fc[o];
        for (int u = 0; u < HH; ++u) acc = fmaf(W_fc[o * HH + u], h1f[u][b], acc);
        out[(size_t)(b0g + b) * 4 + o] = acc;
    }
}

extern "C" void kernel_launch(void* const* d_in, const int* in_sizes, int n_in,
                              void* d_out, int out_size, void* d_ws, size_t ws_size,
                              hipStream_t stream) {
    const float* x     = (const float*)d_in[0];
    const float* W_ih0 = (const float*)d_in[1];
    const float* W_hh0 = (const float*)d_in[2];
    const float* b_ih0 = (const float*)d_in[3];
    const float* b_hh0 = (const float*)d_in[4];
    const float* W_ih1 = (const float*)d_in[5];
    const float* W_hh1 = (const float*)d_in[6];
    const float* b_ih1 = (const float*)d_in[7];
    const float* b_hh1 = (const float*)d_in[8];
    const float* W_fc  = (const float*)d_in[9];
    const float* b_fc  = (const float*)d_in[10];
    float* out = (float*)d_out;

    const int B = 4096;
    dim3 grid(B / BB), block(NTHR);
    lstm2_pk2<<<grid, block, 0, stream>>>(
        x, W_ih0, W_hh0, b_ih0, b_hh0, W_ih1, W_hh1, b_ih1, b_hh1, W_fc, b_fc, out);
}